// Round 8
// baseline (227.996 us; speedup 1.0000x reference)
//
#include <hip/hip_runtime.h>
#include <hip/hip_bf16.h>

// ---------------------------------------------------------------------------
// SingleLayerMoE: T=1024 tokens, H=1024, E=8 experts, I=1024, top-2 routing.
// R12: k_cvt ELIMINATED. GEMMs read fp32 weights directly and convert in
//      register staging (load float4 -> cvt_pk_bf16 -> ds_write), inside the
//      R8-proven counted-vmcnt schedule adapted to reg-staging: 2 LDS buffers
//      + 2 register sets, loads issued 3 phases ahead, in-loop
//      s_waitcnt vmcnt(10/6) (never 0), lgkmcnt(0)+raw barrier per phase.
//      Weights move over HBM exactly once (96 MB, was 192 MB + 43 us kernel).
//      All LDS strides 144 B: read banks 2-way free, write ~2-4-way.
//      Launches: zero, router, gateup, down.
// ---------------------------------------------------------------------------

typedef unsigned short u16;
typedef __attribute__((ext_vector_type(8))) __bf16 bf16x8;
typedef __attribute__((ext_vector_type(4))) float f32x4;

#define T_TOK 1024
#define H_DIM 1024
#define E_NUM 8
#define I_DIM 1024
#define ALPHA 1.702f
#define LIMIT 7.0f

__device__ __forceinline__ u16 f2bf(float f) {
    unsigned u = __builtin_bit_cast(unsigned, f);
    u = (u + 0x7FFFu + ((u >> 16) & 1u)) >> 16;
    return (u16)u;
}

__device__ __forceinline__ unsigned pk2(float lo, float hi) {
#if defined(__has_builtin) && __has_builtin(__builtin_amdgcn_cvt_pk_bf16_f32)
    typedef __attribute__((ext_vector_type(2))) __bf16 bf16x2_t;
    bf16x2_t v = __builtin_amdgcn_cvt_pk_bf16_f32(lo, hi);
    return __builtin_bit_cast(unsigned, v);
#else
    return (unsigned)f2bf(lo) | ((unsigned)f2bf(hi) << 16);
#endif
}

__device__ __forceinline__ f32x4 mfma16(bf16x8 a, bf16x8 b, f32x4 c) {
    return __builtin_amdgcn_mfma_f32_16x16x32_bf16(a, b, c, 0, 0, 0);
}

__device__ __forceinline__ void expert_range(const int* counts, int e,
                                             int& cnt, int& abase) {
    int a = 0, c = 0;
#pragma unroll
    for (int i = 0; i < E_NUM; ++i) {
        int v = counts[i];
        if (i < e) a += v;
        if (i == e) c = v;
    }
    cnt = c; abase = a;
}

// --------------------------- K0: zero counters ------------------------------
__global__ void k_zero(int* counts) {
    if (threadIdx.x < E_NUM) counts[threadIdx.x] = 0;
}

// ------------- K1: router + dispatch + x->bf16 + weighted-bias out ----------
__global__ __launch_bounds__(256) void k_router(
    const float* __restrict__ x, const float* __restrict__ rw,
    const float* __restrict__ rb, const float* __restrict__ db,
    int* __restrict__ counts, int* __restrict__ tok_list,
    float* __restrict__ w_list, u16* __restrict__ xb,
    float* __restrict__ out)
{
    const int t = blockIdx.x;
    const int tid = threadIdx.x;
    const float4 xv = *(const float4*)(x + (size_t)t * H_DIM + tid * 4);

    *(uint2*)(xb + (size_t)t * H_DIM + tid * 4) =
        make_uint2(pk2(xv.x, xv.y), pk2(xv.z, xv.w));

    float p[E_NUM];
#pragma unroll
    for (int e = 0; e < E_NUM; ++e) {
        const float4 wv = *(const float4*)(rw + e * H_DIM + tid * 4);
        p[e] = xv.x * wv.x + xv.y * wv.y + xv.z * wv.z + xv.w * wv.w;
    }
#pragma unroll
    for (int off = 32; off; off >>= 1) {
#pragma unroll
        for (int e = 0; e < E_NUM; ++e) p[e] += __shfl_down(p[e], off, 64);
    }
    __shared__ float red[4][E_NUM];
    __shared__ int se[2];
    __shared__ float sw[2];
    const int lane = tid & 63, wvid = tid >> 6;
    if (lane == 0) {
#pragma unroll
        for (int e = 0; e < E_NUM; ++e) red[wvid][e] = p[e];
    }
    __syncthreads();
    if (tid == 0) {
        float lg[E_NUM];
#pragma unroll
        for (int e = 0; e < E_NUM; ++e)
            lg[e] = red[0][e] + red[1][e] + red[2][e] + red[3][e] + rb[e];
        float m1 = -1e30f, m2 = -1e30f; int i1 = 0, i2 = 0;
#pragma unroll
        for (int e = 0; e < E_NUM; ++e) {
            float l = lg[e];
            if (l > m1) { m2 = m1; i2 = i1; m1 = l; i1 = e; }
            else if (l > m2) { m2 = l; i2 = e; }
        }
        float s = 0.f;
#pragma unroll
        for (int e = 0; e < E_NUM; ++e) s += __expf(lg[e] - m1);
        const float w0 = 1.0f / s;
        const float w1 = __expf(m2 - m1) / s;
        int slot0 = atomicAdd(&counts[i1], 1);
        tok_list[i1 * T_TOK + slot0] = t;
        w_list[i1 * T_TOK + slot0] = w0;
        int slot1 = atomicAdd(&counts[i2], 1);
        tok_list[i2 * T_TOK + slot1] = t;
        w_list[i2 * T_TOK + slot1] = w1;
        se[0] = i1; se[1] = i2; sw[0] = w0; sw[1] = w1;
    }
    __syncthreads();
    const int e0 = se[0], e1 = se[1];
    const float w0 = sw[0], w1 = sw[1];
    const int c = tid * 4;
    float4 d0 = *(const float4*)(db + e0 * H_DIM + c);
    float4 d1 = *(const float4*)(db + e1 * H_DIM + c);
    float4 o;
    o.x = w0 * d0.x + w1 * d1.x;
    o.y = w0 * d0.y + w1 * d1.y;
    o.z = w0 * d0.z + w1 * d1.z;
    o.w = w0 * d0.w + w1 * d1.w;
    *(float4*)(out + (size_t)t * H_DIM + c) = o;
}

// --------------------------- K2: gate_up GEMM + GLU -------------------------
// tile 64m x 128out (64g+64u), BK=64, 16 phases. Reg-staged fused conversion:
// per phase/thread 8 fp32x4 weight loads + 2 uint4 A loads -> 16 pk2 + 16 b32
// + 2 b128 LDS writes. 2 LDS buffers (54 KB -> 2 blk/CU), 2 reg sets, loads
// 3 phases ahead, vmcnt(10) counted waits. grid (16 strips, 16 m, 8 e).
__global__ __launch_bounds__(256, 2) void k_gateup(
    const float* __restrict__ gup, const float* __restrict__ gub,
    const int* __restrict__ counts, const int* __restrict__ tok_list,
    const u16* __restrict__ xb, u16* __restrict__ act)
{
    const int e = blockIdx.z;
    int cnt, abase;
    expert_range(counts, e, cnt, abase);
    const int m0 = blockIdx.y * 64;
    if (m0 >= cnt) return;
    const int n0 = blockIdx.x * 64;            // gate cols n0.., up cols 1024+n0..
    const int tid = threadIdx.x;
    const int lane = tid & 63, wv = tid >> 6;
    const int fm = lane & 15, kg = lane >> 4;
    const int wm = wv >> 1, wn = wv & 1;

    __shared__ __align__(16) u16 As[2][64 * 72];    //  9216 B each
    __shared__ __align__(16) u16 Bs[2][128 * 72];   // 18432 B each
    unsigned* const Bs32[2] = {(unsigned*)Bs[0], (unsigned*)Bs[1]};

    // staging coords: B: kq = k-pair (tid>>3), cq = col-quad (tid&7);
    //                 A: arow = tid>>2, kc = 16-elem k-chunk (tid&3).
    const int kq = tid >> 3, cq = tid & 7;
    const int arow = tid >> 2, kc = tid & 3;
    const int aslot = m0 + arow;
    const int atok = (aslot < cnt) ? tok_list[e * T_TOK + aslot] : 0;
    const u16* gA = xb + (size_t)atok * H_DIM;
    const float* gB = gup + ((size_t)e << 21) + n0;

    float4 Bf[2][2][2][2];   // [set][sub][half][j]
    uint4 Aa[2][2];          // [set][h]

    f32x4 accg[2][2], accu[2][2];
#pragma unroll
    for (int m = 0; m < 2; ++m)
#pragma unroll
        for (int n = 0; n < 2; ++n) {
            accg[m][n] = (f32x4){0.f, 0.f, 0.f, 0.f};
            accu[m][n] = (f32x4){0.f, 0.f, 0.f, 0.f};
        }

    // 8 B loads then 2 A loads = 10 vm ops per stage (vmcnt counted in order)
#define GU_LOADS(S, KB)                                                        \
    {                                                                          \
        _Pragma("unroll")                                                      \
        for (int sub = 0; sub < 2; ++sub)                                      \
        _Pragma("unroll")                                                      \
        for (int half = 0; half < 2; ++half)                                   \
        _Pragma("unroll")                                                      \
        for (int j = 0; j < 2; ++j)                                            \
            Bf[S][sub][half][j] = *(const float4*)(gB +                        \
                (size_t)((KB) + 2 * kq + j) * 2048 + half * 1024 +             \
                sub * 32 + cq * 4);                                            \
        Aa[S][0] = *(const uint4*)(gA + (KB) + kc * 16);                       \
        Aa[S][1] = *(const uint4*)(gA + (KB) + kc * 16 + 8);                   \
    }
#define GU_WRITE(S, BUF)                                                       \
    {                                                                          \
        _Pragma("unroll")                                                      \
        for (int sub = 0; sub < 2; ++sub)                                      \
        _Pragma("unroll")                                                      \
        for (int half = 0; half < 2; ++half)                                   \
        _Pragma("unroll")                                                      \
        for (int c = 0; c < 4; ++c) {                                          \
            const float* j0 = (const float*)&Bf[S][sub][half][0];              \
            const float* j1 = (const float*)&Bf[S][sub][half][1];              \
            Bs32[BUF][(half * 64 + sub * 32 + cq * 4 + c) * 36 + kq] =         \
                pk2(j0[c], j1[c]);                                             \
        }                                                                      \
        *(uint4*)&As[BUF][arow * 72 + kc * 16]     = Aa[S][0];                 \
        *(uint4*)&As[BUF][arow * 72 + kc * 16 + 8] = Aa[S][1];                 \
    }
#define GU_MFMA(BUF)                                                           \
    {                                                                          \
        _Pragma("unroll")                                                      \
        for (int ks = 0; ks < 2; ++ks) {                                       \
            const int ko = ks * 32 + kg * 8;                                   \
            bf16x8 a0 = *(const bf16x8*)&As[BUF][(wm * 32 + fm) * 72 + ko];        \
            bf16x8 a1 = *(const bf16x8*)&As[BUF][(wm * 32 + 16 + fm) * 72 + ko];   \
            bf16x8 bg0 = *(const bf16x8*)&Bs[BUF][(wn * 32 + fm) * 72 + ko];       \
            bf16x8 bg1 = *(const bf16x8*)&Bs[BUF][(wn * 32 + 16 + fm) * 72 + ko];  \
            bf16x8 bu0 = *(const bf16x8*)&Bs[BUF][(64 + wn * 32 + fm) * 72 + ko];  \
            bf16x8 bu1 = *(const bf16x8*)&Bs[BUF][(64 + wn * 32 + 16 + fm) * 72 + ko]; \
            accg[0][0] = mfma16(a0, bg0, accg[0][0]);                          \
            accg[0][1] = mfma16(a0, bg1, accg[0][1]);                          \
            accu[0][0] = mfma16(a0, bu0, accu[0][0]);                          \
            accu[0][1] = mfma16(a0, bu1, accu[0][1]);                          \
            accg[1][0] = mfma16(a1, bg0, accg[1][0]);                          \
            accg[1][1] = mfma16(a1, bg1, accg[1][1]);                          \
            accu[1][0] = mfma16(a1, bu0, accu[1][0]);                          \
            accu[1][1] = mfma16(a1, bu1, accu[1][1]);                          \
        }                                                                      \
    }

    // prologue: L0->set0, L1->set1; W(0); L2->set0; barrier
    GU_LOADS(0, 0);
    GU_LOADS(1, 64);
    asm volatile("s_waitcnt vmcnt(10)" ::: "memory");   // L0 complete
    GU_WRITE(0, 0);
    GU_LOADS(0, 128);
    asm volatile("s_waitcnt lgkmcnt(0)" ::: "memory");
    __builtin_amdgcn_s_barrier();

#pragma unroll
    for (int t = 0; t < 16; ++t) {
        // entering iter t: buf[t&1] ready; regs hold L(t+1) (older), L(t+2) (newer)
        if (t <= 13)      { asm volatile("s_waitcnt vmcnt(10)" ::: "memory"); }
        else if (t == 14) { asm volatile("s_waitcnt vmcnt(0)"  ::: "memory"); }
        if (t + 1 < 16) GU_WRITE((t + 1) & 1, (t + 1) & 1);
        if (t + 3 < 16) GU_LOADS((t + 3) & 1, (t + 3) * 64);
        GU_MFMA(t & 1);
        if (t + 1 < 16) {
            asm volatile("s_waitcnt lgkmcnt(0)" ::: "memory");
            __builtin_amdgcn_s_barrier();
        }
    }
#undef GU_LOADS
#undef GU_WRITE
#undef GU_MFMA

    // epilogue: bias + clamped GLU -> compact bf16 act rows
#pragma unroll
    for (int m = 0; m < 2; ++m) {
#pragma unroll
        for (int r = 0; r < 4; ++r) {
            int row = wm * 32 + m * 16 + kg * 4 + r;   // C/D: row=(lane>>4)*4+reg
            int slot = m0 + row;
            if (slot >= cnt) continue;
            size_t arowo = (size_t)(abase + slot) * I_DIM;
#pragma unroll
            for (int n = 0; n < 2; ++n) {
                int cn = n0 + wn * 32 + n * 16 + fm;   // C/D: col=lane&15
                float g = accg[m][n][r] + gub[e * 2048 + cn];
                float u = accu[m][n][r] + gub[e * 2048 + 1024 + cn];
                g = fminf(g, LIMIT);
                u = fminf(fmaxf(u, -LIMIT), LIMIT);
                float glu = g / (1.f + __expf(-ALPHA * g));
                act[arowo + cn] = f2bf((u + 1.f) * glu);
            }
        }
    }
}

// ---------------- K3: down GEMM * w, atomic combine into out ----------------
// tile 64x64, K=1024, 16 phases. Reg-staged: 4 fp32x4 B loads + 2 uint4 A
// loads per phase/thread (vmcnt 6). 2 LDS buffers (36 KB -> 4 blk/CU).
// grid (16 strips, 16 m, 8 e).
__global__ __launch_bounds__(256, 4) void k_down(
    const float* __restrict__ dp,
    const int* __restrict__ counts, const int* __restrict__ tok_list,
    const float* __restrict__ w_list,
    const u16* __restrict__ act, float* __restrict__ out)
{
    const int e = blockIdx.z;
    int cnt, abase;
    expert_range(counts, e, cnt, abase);
    const int m0 = blockIdx.y * 64;
    if (m0 >= cnt) return;
    const int n0 = blockIdx.x * 64;
    const int tid = threadIdx.x;
    const int lane = tid & 63, wv = tid >> 6;
    const int fm = lane & 15, kg = lane >> 4;
    const int wm = wv >> 1, wn = wv & 1;

    __shared__ __align__(16) u16 As[2][64 * 72];   // 9216 B each
    __shared__ __align__(16) u16 Bs[2][64 * 72];   // 9216 B each
    unsigned* const Bs32[2] = {(unsigned*)Bs[0], (unsigned*)Bs[1]};

    const int kq = tid >> 3, cq = tid & 7;
    const int arow = tid >> 2, kc = tid & 3;
    // rows past cnt read slack act rows (allocated), masked at store
    const u16* gA = act + (size_t)(abase + m0 + arow) * I_DIM;
    const float* gB = dp + ((size_t)e << 20) + n0;

    float4 Bf[2][2][2];   // [set][sub][j]
    uint4 Aa[2][2];

    f32x4 acc[2][2];
#pragma unroll
    for (int m = 0; m < 2; ++m)
#pragma unroll
        for (int n = 0; n < 2; ++n) acc[m][n] = (f32x4){0.f, 0.f, 0.f, 0.f};

#define DN_LOADS(S, KB)                                                        \
    {                                                                          \
        _Pragma("unroll")                                                      \
        for (int sub = 0; sub < 2; ++sub)                                      \
        _Pragma("unroll")                                                      \
        for (int j = 0; j < 2; ++j)                                            \
            Bf[S][sub][j] = *(const float4*)(gB +                              \
                (size_t)((KB) + 2 * kq + j) * 1024 + sub * 32 + cq * 4);       \
        Aa[S][0] = *(const uint4*)(gA + (KB) + kc * 16);                       \
        Aa[S][1] = *(const uint4*)(gA + (KB) + kc * 16 + 8);                   \
    }
#define DN_WRITE(S, BUF)                                                       \
    {                                                                          \
        _Pragma("unroll")                                                      \
        for (int sub = 0; sub < 2; ++sub)                                      \
        _Pragma("unroll")                                                      \
        for (int c = 0; c < 4; ++c) {                                          \
            const float* j0 = (const float*)&Bf[S][sub][0];                    \
            const float* j1 = (const float*)&Bf[S][sub][1];                    \
            Bs32[BUF][(sub * 32 + cq * 4 + c) * 36 + kq] = pk2(j0[c], j1[c]);  \
        }                                                                      \
        *(uint4*)&As[BUF][arow * 72 + kc * 16]     = Aa[S][0];                 \
        *(uint4*)&As[BUF][arow * 72 + kc * 16 + 8] = Aa[S][1];                 \
    }
#define DN_MFMA(BUF)                                                           \
    {                                                                          \
        _Pragma("unroll")                                                      \
        for (int ks = 0; ks < 2; ++ks) {                                       \
            const int ko = ks * 32 + kg * 8;                                   \
            bf16x8 a0 = *(const bf16x8*)&As[BUF][(wm * 32 + fm) * 72 + ko];      \
            bf16x8 a1 = *(const bf16x8*)&As[BUF][(wm * 32 + 16 + fm) * 72 + ko]; \
            bf16x8 b0 = *(const bf16x8*)&Bs[BUF][(wn * 32 + fm) * 72 + ko];      \
            bf16x8 b1 = *(const bf16x8*)&Bs[BUF][(wn * 32 + 16 + fm) * 72 + ko]; \
            acc[0][0] = mfma16(a0, b0, acc[0][0]);                             \
            acc[0][1] = mfma16(a0, b1, acc[0][1]);                             \
            acc[1][0] = mfma16(a1, b0, acc[1][0]);                             \
            acc[1][1] = mfma16(a1, b1, acc[1][1]);                             \
        }                                                                      \
    }

    DN_LOADS(0, 0);
    DN_LOADS(1, 64);
    asm volatile("s_waitcnt vmcnt(6)" ::: "memory");    // L0 complete
    DN_WRITE(0, 0);
    DN_LOADS(0, 128);
    asm volatile("s_waitcnt lgkmcnt(0)" ::: "memory");
    __builtin_amdgcn_s_barrier();

#pragma unroll
    for (int t = 0; t < 16; ++t) {
        if (t <= 13)      { asm volatile("s_waitcnt vmcnt(6)" ::: "memory"); }
        else if (t == 14) { asm volatile("s_waitcnt vmcnt(0)" ::: "memory"); }
        if (t + 1 < 16) DN_WRITE((t + 1) & 1, (t + 1) & 1);
        if (t + 3 < 16) DN_LOADS((t + 3) & 1, (t + 3) * 64);
        DN_MFMA(t & 1);
        if (t + 1 < 16) {
            asm volatile("s_waitcnt lgkmcnt(0)" ::: "memory");
            __builtin_amdgcn_s_barrier();
        }
    }
#undef DN_LOADS
#undef DN_WRITE
#undef DN_MFMA

#pragma unroll
    for (int m = 0; m < 2; ++m) {
#pragma unroll
        for (int r = 0; r < 4; ++r) {
            int row = wm * 32 + m * 16 + kg * 4 + r;
            int slot = m0 + row;
            if (slot >= cnt) continue;
            float wgt = w_list[e * T_TOK + slot];
            int tok = tok_list[e * T_TOK + slot];
            float* orow = out + (size_t)tok * H_DIM;
#pragma unroll
            for (int n = 0; n < 2; ++n) {
                int col = n0 + wn * 32 + n * 16 + fm;
                atomicAdd(orow + col, acc[m][n][r] * wgt);
            }
        }
    }
}

// ---------------------------------------------------------------------------
extern "C" void kernel_launch(void* const* d_in, const int* in_sizes, int n_in,
                              void* d_out, int out_size, void* d_ws, size_t ws_size,
                              hipStream_t stream) {
    const float* x   = (const float*)d_in[0]; // [1,1024,1024]
    const float* rw  = (const float*)d_in[1]; // [8,1024]
    const float* rb  = (const float*)d_in[2]; // [8]
    const float* gup = (const float*)d_in[3]; // [8,1024,2048]
    const float* gub = (const float*)d_in[4]; // [8,2048]
    const float* dp  = (const float*)d_in[5]; // [8,1024,1024]
    const float* db  = (const float*)d_in[6]; // [8,1024]
    float* out = (float*)d_out;

    char* ws = (char*)d_ws;
    int*   counts   = (int*)(ws);                    // 8 ints
    int*   tok_list = (int*)(ws + 64);               // 8*1024 ints (32 KB)
    float* w_list   = (float*)(ws + 64 + 32768);     // 8*1024 f32  (32 KB)
    u16*   xb       = (u16*)(ws + 65600);            // 1024*1024 bf16 (2 MB)
    u16*   act      = (u16*)(ws + 65600 + 2097152);  // 2112 rows bf16 (+slack)

    k_zero<<<1, 64, 0, stream>>>(counts);
    k_router<<<T_TOK, 256, 0, stream>>>(x, rw, rb, db, counts, tok_list, w_list,
                                        xb, out);
    k_gateup<<<dim3(16, 16, 8), 256, 0, stream>>>(gup, gub, counts, tok_list,
                                                  xb, act);
    k_down<<<dim3(16, 16, 8), 256, 0, stream>>>(dp, counts, tok_list, w_list,
                                                act, out);
}

// Round 9
// 205.306 us; speedup vs baseline: 1.1105x; 1.1105x over previous
//
#include <hip/hip_runtime.h>
#include <hip/hip_bf16.h>

// ---------------------------------------------------------------------------
// SingleLayerMoE: T=1024 tokens, H=1024, E=8 experts, I=1024, top-2 routing.
// R13: R8 verbatim (measured optimum: 207.5 us) with two serialization fixes:
//      (1) router merged into cvt's grid as blocks 6144..7167 (block-uniform
//      branch, LDS union) -> router traffic overlaps cvt streaming, one fewer
//      launch gap; (2) counts zeroed via hipMemsetAsync (graph-capture-safe)
//      instead of a k_zero launch. GEMM kernels untouched.
//      Measured history: R9 (32x32/128-tiles) 238, R10 (BK=32) 220, R11 (cvt
//      rebuild) 214, R12 (fused reg-staging cvt) 228 -> all reverted.
// ---------------------------------------------------------------------------

typedef unsigned short u16;
typedef __attribute__((ext_vector_type(8))) __bf16 bf16x8;
typedef __attribute__((ext_vector_type(4))) float f32x4;

#define T_TOK 1024
#define H_DIM 1024
#define E_NUM 8
#define I_DIM 1024
#define ALPHA 1.702f
#define LIMIT 7.0f

__device__ __forceinline__ u16 f2bf(float f) {
    unsigned u = __builtin_bit_cast(unsigned, f);
    u = (u + 0x7FFFu + ((u >> 16) & 1u)) >> 16;
    return (u16)u;
}

__device__ __forceinline__ unsigned pk2(float lo, float hi) {
#if defined(__has_builtin) && __has_builtin(__builtin_amdgcn_cvt_pk_bf16_f32)
    typedef __attribute__((ext_vector_type(2))) __bf16 bf16x2_t;
    bf16x2_t v = __builtin_amdgcn_cvt_pk_bf16_f32(lo, hi);
    return __builtin_bit_cast(unsigned, v);
#else
    return (unsigned)f2bf(lo) | ((unsigned)f2bf(hi) << 16);
#endif
}

__device__ __forceinline__ f32x4 mfma16(bf16x8 a, bf16x8 b, f32x4 c) {
    return __builtin_amdgcn_mfma_f32_16x16x32_bf16(a, b, c, 0, 0, 0);
}

// async global->LDS, 16B per lane; LDS dest is wave-uniform base + lane*16.
__device__ __forceinline__ void gld16(const void* g, void* l) {
    __builtin_amdgcn_global_load_lds(
        (const __attribute__((address_space(1))) void*)g,
        (__attribute__((address_space(3))) void*)l, 16, 0, 0);
}

__device__ __forceinline__ void expert_range(const int* counts, int e,
                                             int& cnt, int& abase) {
    int a = 0, c = 0;
#pragma unroll
    for (int i = 0; i < E_NUM; ++i) {
        int v = counts[i];
        if (i < e) a += v;
        if (i == e) c = v;
    }
    cnt = c; abase = a;
}

// ---- K0: fused {weight fp32->bf16 transpose} + {router/dispatch} ----------
// blocks 0..6143: cvt tiles (gup 4096, dp 2048), 64x64, 4x4 reg transpose.
// blocks 6144..7167: router for token t = b - 6144 (counts pre-zeroed by
// hipMemsetAsync on the stream). Block-uniform branch; LDS union.
__global__ __launch_bounds__(256) void k_cvt_router(
    const float* __restrict__ gup, const float* __restrict__ dp,
    u16* __restrict__ gupT, u16* __restrict__ dpT,
    const float* __restrict__ x, const float* __restrict__ rw,
    const float* __restrict__ rb, const float* __restrict__ db,
    int* __restrict__ counts, int* __restrict__ tok_list,
    float* __restrict__ w_list, u16* __restrict__ xb,
    float* __restrict__ out)
{
    __shared__ __align__(16) u16 shmem[64 * 72];   // 9216 B (cvt Ls / router red)
    const int b = blockIdx.x;
    const int tid = threadIdx.x;

    if (b < 6144) {
        // ---------------- cvt path (R7/R8-proven) ----------------
        const float* src; u16* dst; int C, k0, c0;
        if (b < 4096) {                       // gup: 512 tiles/expert
            int e = b >> 9, t = b & 511;
            k0 = (t >> 5) * 64; c0 = (t & 31) * 64;
            src = gup + ((size_t)e << 21); dst = gupT + ((size_t)e << 21); C = 2048;
        } else {                              // dp: 256 tiles/expert
            int b2 = b - 4096;
            int e = b2 >> 8, t = b2 & 255;
            k0 = (t >> 4) * 64; c0 = (t & 15) * 64;
            src = dp + ((size_t)e << 20); dst = dpT + ((size_t)e << 20); C = 1024;
        }
        u16 (*Ls)[72] = (u16(*)[72])shmem;
        const int kq = tid >> 4, cq = tid & 15;
        float4 v0 = *(const float4*)(src + (size_t)(k0 + kq * 4 + 0) * C + c0 + cq * 4);
        float4 v1 = *(const float4*)(src + (size_t)(k0 + kq * 4 + 1) * C + c0 + cq * 4);
        float4 v2 = *(const float4*)(src + (size_t)(k0 + kq * 4 + 2) * C + c0 + cq * 4);
        float4 v3 = *(const float4*)(src + (size_t)(k0 + kq * 4 + 3) * C + c0 + cq * 4);
        const float* p0 = (const float*)&v0; const float* p1 = (const float*)&v1;
        const float* p2 = (const float*)&v2; const float* p3 = (const float*)&v3;
#pragma unroll
        for (int i = 0; i < 4; ++i) {
            *(uint2*)&Ls[cq * 4 + i][kq * 4] =
                make_uint2(pk2(p0[i], p1[i]), pk2(p2[i], p3[i]));
        }
        __syncthreads();
        const int oc = tid >> 2, och = (tid & 3) * 16;
        u16* orow = dst + (size_t)(c0 + oc) * 1024 + k0 + och;
        *(uint4*)(orow)     = *(uint4*)&Ls[oc][och];
        *(uint4*)(orow + 8) = *(uint4*)&Ls[oc][och + 8];
        return;
    }

    // ---------------- router path (R8-proven) ----------------
    const int t = b - 6144;
    float* red = (float*)shmem;                       // [4][E_NUM]
    int*   se  = (int*)(shmem + 64 * 36);             // [2]
    float* sw  = (float*)(shmem + 64 * 36 + 8);       // [2]

    const float4 xv = *(const float4*)(x + (size_t)t * H_DIM + tid * 4);
    *(uint2*)(xb + (size_t)t * H_DIM + tid * 4) =
        make_uint2(pk2(xv.x, xv.y), pk2(xv.z, xv.w));

    float p[E_NUM];
#pragma unroll
    for (int e = 0; e < E_NUM; ++e) {
        const float4 wv = *(const float4*)(rw + e * H_DIM + tid * 4);
        p[e] = xv.x * wv.x + xv.y * wv.y + xv.z * wv.z + xv.w * wv.w;
    }
#pragma unroll
    for (int off = 32; off; off >>= 1) {
#pragma unroll
        for (int e = 0; e < E_NUM; ++e) p[e] += __shfl_down(p[e], off, 64);
    }
    const int lane = tid & 63, wvid = tid >> 6;
    if (lane == 0) {
#pragma unroll
        for (int e = 0; e < E_NUM; ++e) red[wvid * E_NUM + e] = p[e];
    }
    __syncthreads();
    if (tid == 0) {
        float lg[E_NUM];
#pragma unroll
        for (int e = 0; e < E_NUM; ++e)
            lg[e] = red[0 * E_NUM + e] + red[1 * E_NUM + e] +
                    red[2 * E_NUM + e] + red[3 * E_NUM + e] + rb[e];
        float m1 = -1e30f, m2 = -1e30f; int i1 = 0, i2 = 0;
#pragma unroll
        for (int e = 0; e < E_NUM; ++e) {
            float l = lg[e];
            if (l > m1) { m2 = m1; i2 = i1; m1 = l; i1 = e; }
            else if (l > m2) { m2 = l; i2 = e; }
        }
        float s = 0.f;
#pragma unroll
        for (int e = 0; e < E_NUM; ++e) s += __expf(lg[e] - m1);
        const float w0 = 1.0f / s;
        const float w1 = __expf(m2 - m1) / s;
        int slot0 = atomicAdd(&counts[i1], 1);
        tok_list[i1 * T_TOK + slot0] = t;
        w_list[i1 * T_TOK + slot0] = w0;
        int slot1 = atomicAdd(&counts[i2], 1);
        tok_list[i2 * T_TOK + slot1] = t;
        w_list[i2 * T_TOK + slot1] = w1;
        se[0] = i1; se[1] = i2; sw[0] = w0; sw[1] = w1;
    }
    __syncthreads();
    const int e0 = se[0], e1 = se[1];
    const float w0 = sw[0], w1 = sw[1];
    const int c = tid * 4;
    float4 d0 = *(const float4*)(db + e0 * H_DIM + c);
    float4 d1 = *(const float4*)(db + e1 * H_DIM + c);
    float4 o;
    o.x = w0 * d0.x + w1 * d1.x;
    o.y = w0 * d0.y + w1 * d1.y;
    o.z = w0 * d0.z + w1 * d1.z;
    o.w = w0 * d0.w + w1 * d1.w;
    *(float4*)(out + (size_t)t * H_DIM + c) = o;
}

// --------------------------- K2: gate_up GEMM + GLU -------------------------
// tile 64 rows x 128 outputs (64g+64u), BK=64, 16 phases, 3-buffer counted
// vmcnt pipeline (stage 2 ahead, NL=6), XOR-swizzled LDS. 72 KB -> 2 blk/CU.
__global__ __launch_bounds__(256, 2) void k_gateup(
    const u16* __restrict__ gupT, const float* __restrict__ gub,
    const int* __restrict__ counts, const int* __restrict__ tok_list,
    const u16* __restrict__ xb, u16* __restrict__ act)
{
    const int e = blockIdx.z;
    int cnt, abase;
    expert_range(counts, e, cnt, abase);
    const int m0 = blockIdx.y * 64;
    if (m0 >= cnt) return;
    const int n0 = blockIdx.x * 64;            // gate cols n0.., up cols 1024+n0..
    const int tid = threadIdx.x;
    const int lane = tid & 63, wv = tid >> 6;
    const int fm = lane & 15, kg = lane >> 4;
    const int wm = wv >> 1, wn = wv & 1;

    __shared__ __align__(16) u16 As0[64 * 64], As1[64 * 64], As2[64 * 64];
    __shared__ __align__(16) u16 Bs0[128 * 64], Bs1[128 * 64], Bs2[128 * 64];
    u16* const AB[3] = {As0, As1, As2};
    u16* const BB[3] = {Bs0, Bs1, Bs2};

    // staging: wave writes 1KB chunks; lane l -> row chunk+ (l>>3), slot l&7.
    // Pre-swizzle the GLOBAL source slot by ^row (linear dest, swizzled read).
    const int lr = lane >> 3;
    const int lk = ((lane & 7) ^ lr) * 8;      // swizzled 16B-slot, in u16
    const u16* gA[2];
#pragma unroll
    for (int i = 0; i < 2; ++i) {
        int row = (wv * 2 + i) * 8 + lr;
        int slot = m0 + row;
        int tok = (slot < cnt) ? tok_list[e * T_TOK + slot] : 0;
        gA[i] = xb + (size_t)tok * H_DIM + lk;
    }
    const u16* gB[4];
#pragma unroll
    for (int i = 0; i < 4; ++i) {
        int row = (wv * 4 + i) * 8 + lr;       // 0..127
        int col = (row < 64) ? (n0 + row) : (1024 + n0 + row - 64);
        gB[i] = gupT + ((size_t)e << 21) + (size_t)col * 1024 + lk;
    }

    f32x4 accg[2][2], accu[2][2];
#pragma unroll
    for (int m = 0; m < 2; ++m)
#pragma unroll
        for (int n = 0; n < 2; ++n) {
            accg[m][n] = (f32x4){0.f, 0.f, 0.f, 0.f};
            accu[m][n] = (f32x4){0.f, 0.f, 0.f, 0.f};
        }

#define GU_STAGE(AS, BS, KB)                                                   \
    {                                                                          \
        gld16(gA[0] + (KB), (u16*)(AS) + (wv * 2 + 0) * 512);                  \
        gld16(gA[1] + (KB), (u16*)(AS) + (wv * 2 + 1) * 512);                  \
        gld16(gB[0] + (KB), (u16*)(BS) + (wv * 4 + 0) * 512);                  \
        gld16(gB[1] + (KB), (u16*)(BS) + (wv * 4 + 1) * 512);                  \
        gld16(gB[2] + (KB), (u16*)(BS) + (wv * 4 + 2) * 512);                  \
        gld16(gB[3] + (KB), (u16*)(BS) + (wv * 4 + 3) * 512);                  \
    }
    // read offset: all A/B rows have row&7 == fm&7 -> same swizzled k-offset
#define GU_MFMA(AS, BS)                                                        \
    {                                                                          \
        _Pragma("unroll")                                                      \
        for (int ks = 0; ks < 2; ++ks) {                                       \
            const int ko = (((ks * 4 + kg) ^ (fm & 7)) << 3);                  \
            bf16x8 a0 = *(const bf16x8*)((const u16*)(AS) + (wm * 32 + fm) * 64 + ko);        \
            bf16x8 a1 = *(const bf16x8*)((const u16*)(AS) + (wm * 32 + 16 + fm) * 64 + ko);   \
            bf16x8 bg0 = *(const bf16x8*)((const u16*)(BS) + (wn * 32 + fm) * 64 + ko);       \
            bf16x8 bg1 = *(const bf16x8*)((const u16*)(BS) + (wn * 32 + 16 + fm) * 64 + ko);  \
            bf16x8 bu0 = *(const bf16x8*)((const u16*)(BS) + (64 + wn * 32 + fm) * 64 + ko);  \
            bf16x8 bu1 = *(const bf16x8*)((const u16*)(BS) + (64 + wn * 32 + 16 + fm) * 64 + ko); \
            accg[0][0] = mfma16(a0, bg0, accg[0][0]);                          \
            accg[0][1] = mfma16(a0, bg1, accg[0][1]);                          \
            accu[0][0] = mfma16(a0, bu0, accu[0][0]);                          \
            accu[0][1] = mfma16(a0, bu1, accu[0][1]);                          \
            accg[1][0] = mfma16(a1, bg0, accg[1][0]);                          \
            accg[1][1] = mfma16(a1, bg1, accg[1][1]);                          \
            accu[1][0] = mfma16(a1, bu0, accu[1][0]);                          \
            accu[1][1] = mfma16(a1, bu1, accu[1][1]);                          \
        }                                                                      \
    }

    GU_STAGE(AB[0], BB[0], 0);
    GU_STAGE(AB[1], BB[1], 64);
#pragma unroll
    for (int p = 0; p < 16; ++p) {
        // certify stage p landed (only stage p+1's 6 loads may remain);
        // lgkmcnt(0): all ds_reads of prior phase done before buffers reused.
        if (p == 15) { asm volatile("s_waitcnt vmcnt(0) lgkmcnt(0)" ::: "memory"); }
        else         { asm volatile("s_waitcnt vmcnt(6) lgkmcnt(0)" ::: "memory"); }
        __builtin_amdgcn_s_barrier();
        if (p + 2 < 16) GU_STAGE(AB[(p + 2) % 3], BB[(p + 2) % 3], (p + 2) * 64);
        GU_MFMA(AB[p % 3], BB[p % 3]);
    }
#undef GU_STAGE
#undef GU_MFMA

    // epilogue: bias + clamped GLU -> compact bf16 act rows
#pragma unroll
    for (int m = 0; m < 2; ++m) {
#pragma unroll
        for (int r = 0; r < 4; ++r) {
            int row = wm * 32 + m * 16 + kg * 4 + r;   // C/D: row=(lane>>4)*4+reg
            int slot = m0 + row;
            if (slot >= cnt) continue;
            size_t arow = (size_t)(abase + slot) * I_DIM;
#pragma unroll
            for (int n = 0; n < 2; ++n) {
                int cn = n0 + wn * 32 + n * 16 + fm;   // C/D: col=lane&15
                float g = accg[m][n][r] + gub[e * 2048 + cn];
                float u = accu[m][n][r] + gub[e * 2048 + 1024 + cn];
                g = fminf(g, LIMIT);
                u = fminf(fmaxf(u, -LIMIT), LIMIT);
                float glu = g / (1.f + __expf(-ALPHA * g));
                act[arow + cn] = f2bf((u + 1.f) * glu);
            }
        }
    }
}

// ---------------- K3: down GEMM * w, atomic combine into out ----------------
// tile 64x64, K=1024, 16 phases, 3-buffer counted vmcnt (NL=4), swizzled LDS.
// 48 KB -> 3 blk/CU.
__global__ __launch_bounds__(256, 3) void k_down(
    const u16* __restrict__ dpT,
    const int* __restrict__ counts, const int* __restrict__ tok_list,
    const float* __restrict__ w_list,
    const u16* __restrict__ act, float* __restrict__ out)
{
    const int e = blockIdx.z;
    int cnt, abase;
    expert_range(counts, e, cnt, abase);
    const int m0 = blockIdx.y * 64;
    if (m0 >= cnt) return;
    const int n0 = blockIdx.x * 64;
    const int tid = threadIdx.x;
    const int lane = tid & 63, wv = tid >> 6;
    const int fm = lane & 15, kg = lane >> 4;
    const int wm = wv >> 1, wn = wv & 1;

    __shared__ __align__(16) u16 As0[64 * 64], As1[64 * 64], As2[64 * 64];
    __shared__ __align__(16) u16 Bs0[64 * 64], Bs1[64 * 64], Bs2[64 * 64];
    u16* const AB[3] = {As0, As1, As2};
    u16* const BB[3] = {Bs0, Bs1, Bs2};

    const int lr = lane >> 3;
    const int lk = ((lane & 7) ^ lr) * 8;      // pre-swizzled source slot
    const u16* gA[2];
    const u16* gB[2];
#pragma unroll
    for (int i = 0; i < 2; ++i) {
        int row = (wv * 2 + i) * 8 + lr;
        gA[i] = act + (size_t)(abase + m0 + row) * I_DIM + lk;
        gB[i] = dpT + ((size_t)e << 20) + (size_t)(n0 + row) * 1024 + lk;
    }

    f32x4 acc[2][2];
#pragma unroll
    for (int m = 0; m < 2; ++m)
#pragma unroll
        for (int n = 0; n < 2; ++n) acc[m][n] = (f32x4){0.f, 0.f, 0.f, 0.f};

#define DN_STAGE(AS, BS, KB)                                                   \
    {                                                                          \
        gld16(gA[0] + (KB), (u16*)(AS) + (wv * 2 + 0) * 512);                  \
        gld16(gA[1] + (KB), (u16*)(AS) + (wv * 2 + 1) * 512);                  \
        gld16(gB[0] + (KB), (u16*)(BS) + (wv * 2 + 0) * 512);                  \
        gld16(gB[1] + (KB), (u16*)(BS) + (wv * 2 + 1) * 512);                  \
    }
#define DN_MFMA(AS, BS)                                                        \
    {                                                                          \
        _Pragma("unroll")                                                      \
        for (int ks = 0; ks < 2; ++ks) {                                       \
            const int ko = (((ks * 4 + kg) ^ (fm & 7)) << 3);                  \
            bf16x8 a0 = *(const bf16x8*)((const u16*)(AS) + (wm * 32 + fm) * 64 + ko);      \
            bf16x8 a1 = *(const bf16x8*)((const u16*)(AS) + (wm * 32 + 16 + fm) * 64 + ko); \
            bf16x8 b0 = *(const bf16x8*)((const u16*)(BS) + (wn * 32 + fm) * 64 + ko);      \
            bf16x8 b1 = *(const bf16x8*)((const u16*)(BS) + (wn * 32 + 16 + fm) * 64 + ko); \
            acc[0][0] = mfma16(a0, b0, acc[0][0]);                             \
            acc[0][1] = mfma16(a0, b1, acc[0][1]);                             \
            acc[1][0] = mfma16(a1, b0, acc[1][0]);                             \
            acc[1][1] = mfma16(a1, b1, acc[1][1]);                             \
        }                                                                      \
    }

    DN_STAGE(AB[0], BB[0], 0);
    DN_STAGE(AB[1], BB[1], 64);
#pragma unroll
    for (int p = 0; p < 16; ++p) {
        if (p == 15) { asm volatile("s_waitcnt vmcnt(0) lgkmcnt(0)" ::: "memory"); }
        else         { asm volatile("s_waitcnt vmcnt(4) lgkmcnt(0)" ::: "memory"); }
        __builtin_amdgcn_s_barrier();
        if (p + 2 < 16) DN_STAGE(AB[(p + 2) % 3], BB[(p + 2) % 3], (p + 2) * 64);
        DN_MFMA(AB[p % 3], BB[p % 3]);
    }
#undef DN_STAGE
#undef DN_MFMA

#pragma unroll
    for (int m = 0; m < 2; ++m) {
#pragma unroll
        for (int r = 0; r < 4; ++r) {
            int row = wm * 32 + m * 16 + kg * 4 + r;
            int slot = m0 + row;
            if (slot >= cnt) continue;
            float wgt = w_list[e * T_TOK + slot];
            int tok = tok_list[e * T_TOK + slot];
            float* orow = out + (size_t)tok * H_DIM;
#pragma unroll
            for (int n = 0; n < 2; ++n) {
                int col = n0 + wn * 32 + n * 16 + fm;
                atomicAdd(orow + col, acc[m][n][r] * wgt);
            }
        }
    }
}

// ---------------------------------------------------------------------------
extern "C" void kernel_launch(void* const* d_in, const int* in_sizes, int n_in,
                              void* d_out, int out_size, void* d_ws, size_t ws_size,
                              hipStream_t stream) {
    const float* x   = (const float*)d_in[0]; // [1,1024,1024]
    const float* rw  = (const float*)d_in[1]; // [8,1024]
    const float* rb  = (const float*)d_in[2]; // [8]
    const float* gup = (const float*)d_in[3]; // [8,1024,2048]
    const float* gub = (const float*)d_in[4]; // [8,2048]
    const float* dp  = (const float*)d_in[5]; // [8,1024,1024]
    const float* db  = (const float*)d_in[6]; // [8,1024]
    float* out = (float*)d_out;

    char* ws = (char*)d_ws;
    int*   counts   = (int*)(ws);                    // 8 ints
    int*   tok_list = (int*)(ws + 64);               // 8*1024 ints (32 KB)
    float* w_list   = (float*)(ws + 64 + 32768);     // 8*1024 f32  (32 KB)
    u16*   xb       = (u16*)(ws + 65600);            // 1024*1024 bf16 (2 MB)
    u16*   act      = (u16*)(ws + 65600 + 2097152);  // 2112 rows bf16 (+slack)
    u16*   gupT     = (u16*)(ws + 8388608);          // [8][2048][1024] bf16 (32 MB)
    u16*   dpT      = (u16*)(ws + 41943040);         // [8][1024][1024] bf16 (16 MB)

    hipMemsetAsync(counts, 0, E_NUM * sizeof(int), stream);
    k_cvt_router<<<6144 + T_TOK, 256, 0, stream>>>(gup, dp, gupT, dpT,
                                                   x, rw, rb, db, counts,
                                                   tok_list, w_list, xb, out);
    k_gateup<<<dim3(16, 16, 8), 256, 0, stream>>>(gupT, gub, counts, tok_list,
                                                  xb, act);
    k_down<<<dim3(16, 16, 8), 256, 0, stream>>>(dpT, counts, tok_list, w_list,
                                                act, out);
}